// Round 14
// baseline (148.278 us; speedup 1.0000x reference)
//
#include <hip/hip_runtime.h>
#include <stdint.h>

// Expansion + checkerboard-preserving dropout.
// Phase 1: ballot mask kernel — one thread per mask BIT; final mask =
//          (rand>0.25 | center) & in-bounds, packed 3200 u32 in d_ws.
// Phase 2: barrier-free direct-load kernel. 256-thread blocks, 16 contiguous
//          output rows (20 KB) each, linear block->address mapping, 20480
//          blocks. No LDS, no __syncthreads: x (3 KB/block, L1-resident) and
//          mask (12.8 KB chip-wide) are read directly through L1/L2. Inner
//          loop: 1 mask word + 4 x loads + selects + 1 float4 store.

#define KEEP_SCALE (1.0f / 0.75f)

typedef float f32x4 __attribute__((ext_vector_type(4)));

__global__ __launch_bounds__(256) void build_mask_kernel(
    const float* __restrict__ rv,       // (320,320)
    uint32_t* __restrict__ mask)        // 3200 words, 10 per row
{
    const int g  = blockIdx.x * 256 + threadIdx.x;  // bit index, 0..102399
    const int oh = g / 320;
    const int ow = g - oh * 320;

    int qh = oh / 5, rh = oh - qh * 5;
    int ih = qh + rh - 2;
    int q  = ow / 5, r  = ow - q * 5;
    int iw = q + r - 2;

    float v = rv[g];                    // coalesced: 64 consecutive floats/wave
    bool keep = ((v > 0.25f) || (rh == 2 && r == 2))
                && ((unsigned)ih < 64u) && ((unsigned)iw < 64u);

    unsigned long long bal = __ballot(keep);
    int lane = threadIdx.x & 63;
    if (lane == 0)
        mask[g >> 5] = (uint32_t)bal;
    else if (lane == 32)
        mask[g >> 5] = (uint32_t)(bal >> 32);
}

__global__ __launch_bounds__(256) void expand_cps_dropout_kernel(
    const float* __restrict__ x,        // (1024, 64, 64)
    const uint32_t* __restrict__ mask,  // 3200 words (bounds folded in)
    float* __restrict__ out)            // (1024, 320, 320)
{
    const int t  = threadIdx.x;         // 0..255
    const int b  = blockIdx.x;          // 0..20479, LINEAR over output
    const int bc = b / 20;              // image
    const int rg = b - bc * 20;         // 16-row chunk within image
    const int a  = 16 * rg;             // first output row of this block

    const float*    xim  = x + (size_t)bc * 4096;
    const uint32_t* mrow = mask + rg * 160;     // rows a..a+15
    float*          ob   = out + (size_t)b * 5120;

    #pragma unroll
    for (int ji = 0; ji < 5; ++ji) {
        const int f  = t + 256 * ji;    // 0..1279; output addr = ob + 4*f
        const int r0 = f / 80;          // local row 0..15
        const int o4 = f - r0 * 80;     // float4 index in row
        const int ow = o4 * 4;

        // source row (clamped; mask kills OOB)
        const int oh = a + r0;
        const int qh = oh / 5;
        const int rh = oh - qh * 5;
        int ih = qh + rh - 2;
        ih = ih < 0 ? 0 : (ih > 63 ? 63 : ih);
        const float* xr = xim + ih * 64;

        const uint32_t mb = mrow[r0 * 10 + (o4 >> 3)] >> ((o4 & 7) * 4);

        f32x4 o;
        #pragma unroll
        for (int k = 0; k < 4; ++k) {
            int oo = ow + k;
            int q  = oo / 5;
            int r  = oo - q * 5;
            int iw = q + r - 2;
            iw = iw < 0 ? 0 : (iw > 63 ? 63 : iw);   // mask kills OOB
            o[k] = (mb & (1u << k)) ? xr[iw] * KEEP_SCALE : 0.0f;
        }
        *reinterpret_cast<f32x4*>(ob + 4 * f) = o;
    }
}

extern "C" void kernel_launch(void* const* d_in, const int* in_sizes, int n_in,
                              void* d_out, int out_size, void* d_ws, size_t ws_size,
                              hipStream_t stream) {
    const float* x  = (const float*)d_in[0];
    const float* rv = (const float*)d_in[1];
    float* out      = (float*)d_out;
    uint32_t* mask  = (uint32_t*)d_ws;      // 12.8 KB scratch

    hipLaunchKernelGGL(build_mask_kernel, dim3(400), dim3(256), 0, stream, rv, mask);

    dim3 block(256);
    dim3 grid(20480);                       // 1024 images x 20 chunks, linear
    hipLaunchKernelGGL(expand_cps_dropout_kernel, grid, block, 0, stream,
                       x, mask, out);
}

// Round 15
// 137.418 us; speedup vs baseline: 1.0790x; 1.0790x over previous
//
#include <hip/hip_runtime.h>
#include <stdint.h>

// Expansion + checkerboard-preserving dropout.
// Phase 1: ballot mask kernel — one thread per mask BIT; final mask =
//          (rand>0.25 | center) & in-bounds, packed 3200 u32 in d_ws.
// Phase 2: static-window kernel. 256-thread blocks = 32 rows x 8 segs of 40
//          cols; 40 KB output per block, linear mapping, 10240 blocks.
//          x staged in LDS shifted by +2 slots (row stride 76 floats) so each
//          seg's 12-float source window [8a-2, 8a+9] is 3 aligned ds_read_b128.
//          Output->window mapping j=(o/5)+(o%5) is compile-time static: the
//          inner loop is pure cndmask from premultiplied registers + stores.

#define KEEP_SCALE (1.0f / 0.75f)

typedef float f32x4 __attribute__((ext_vector_type(4)));

__global__ __launch_bounds__(256) void build_mask_kernel(
    const float* __restrict__ rv,       // (320,320)
    uint32_t* __restrict__ mask)        // 3200 words, 10 per row
{
    const int g  = blockIdx.x * 256 + threadIdx.x;  // bit index, 0..102399
    const int oh = g / 320;
    const int ow = g - oh * 320;

    int qh = oh / 5, rh = oh - qh * 5;
    int ih = qh + rh - 2;
    int q  = ow / 5, r  = ow - q * 5;
    int iw = q + r - 2;

    float v = rv[g];                    // coalesced: 64 consecutive floats/wave
    bool keep = ((v > 0.25f) || (rh == 2 && r == 2))
                && ((unsigned)ih < 64u) && ((unsigned)iw < 64u);

    unsigned long long bal = __ballot(keep);
    int lane = threadIdx.x & 63;
    if (lane == 0)
        mask[g >> 5] = (uint32_t)bal;
    else if (lane == 32)
        mask[g >> 5] = (uint32_t)(bal >> 32);
}

__global__ __launch_bounds__(256) void expand_cps_dropout_kernel(
    const float* __restrict__ x,        // (1024, 64, 64)
    const uint32_t* __restrict__ mask,  // 3200 words (bounds folded in)
    float* __restrict__ out)            // (1024, 320, 320)
{
    // 12 source rows, stride 76 floats (304 B, 16B-aligned, odd*4 bank step);
    // slot c+2 holds x[ih][c]; slots 0,1,66,67 are garbage (always masked off).
    __shared__ __align__(16) float    xs[12 * 76];
    __shared__ __align__(16) uint32_t ms[320];      // 32 rows x 10 words

    const int t  = threadIdx.x;         // 0..255
    const int b  = blockIdx.x;          // 0..10239, LINEAR over output
    const int bc = b / 10;              // image
    const int rg = b - bc * 10;         // 32-row chunk within image
    const int a0 = 32 * rg;             // first output row

    int s0 = a0 / 5 - 2;                // first staged source row
    s0 = s0 < 0 ? 0 : (s0 > 52 ? 52 : s0);

    // ---- stage: waves 0-2 copy x (reg->LDS, shifted); wave 3 copies mask ----
    if (t < 192) {
        const int row = t >> 4;         // 0..11
        const int c4  = t & 15;         // float4 within 64-float source row
        const f32x4 v = *reinterpret_cast<const f32x4*>(
            x + (size_t)bc * 4096 + (s0 + row) * 64 + c4 * 4);
        float* dst = xs + row * 76 + c4 * 4 + 2;   // byte ≡ 8 (mod 16): two b64s
        float2 lo, hi;
        lo.x = v[0]; lo.y = v[1];
        hi.x = v[2]; hi.y = v[3];
        *reinterpret_cast<float2*>(dst)     = lo;
        *reinterpret_cast<float2*>(dst + 2) = hi;
    } else {
        const int i = t - 192;          // 0..63
        const uint32_t* msrc = mask + rg * 320;    // rows a0..a0+31
        __builtin_amdgcn_global_load_lds(
            (const __attribute__((address_space(1))) void*)(msrc + i * 4),
            (__attribute__((address_space(3))) void*)(ms + (i & ~63) * 4),
            16, 0, 0);
        if (i < 16) {
            __builtin_amdgcn_global_load_lds(
                (const __attribute__((address_space(1))) void*)(msrc + (i + 64) * 4),
                (__attribute__((address_space(3))) void*)(ms + ((i + 64) & ~63) * 4),
                16, 0, 0);
        }
    }
    __syncthreads();

    // ---- per-thread: row + 40-col segment ----
    const int rloc = t >> 3;            // 0..31
    const int a    = t & 7;             // seg: cols [40a, 40a+40)

    const int oh = a0 + rloc;
    const int qh = oh / 5;
    const int rh = oh - qh * 5;
    int ihrel = qh + rh - 2 - s0;
    ihrel = ihrel < 0 ? 0 : (ihrel > 11 ? 11 : ihrel);   // mask kills OOB rows

    // 12-float window: slots [8a, 8a+11] = cols [8a-2, 8a+9]
    const float* wrow = xs + ihrel * 76 + 8 * a;
    f32x4 w0 = *reinterpret_cast<const f32x4*>(wrow);
    f32x4 w1 = *reinterpret_cast<const f32x4*>(wrow + 4);
    f32x4 w2 = *reinterpret_cast<const f32x4*>(wrow + 8);
    w0 *= KEEP_SCALE;
    w1 *= KEEP_SCALE;
    w2 *= KEEP_SCALE;

    // 40 mask bits for this segment
    const int wi = (40 * a) >> 5;
    const int sh = (40 * a) & 31;
    const uint32_t* mrw = ms + rloc * 10;
    uint64_t mm = ((uint64_t)mrw[wi + 1] << 32) | (uint64_t)mrw[wi];
    mm >>= sh;
    const uint32_t m0 = (uint32_t)mm;
    const uint32_t m1 = (uint32_t)(mm >> 32);

    float* orow = out + (size_t)b * 10240 + rloc * 320 + 40 * a;

    #pragma unroll
    for (int p = 0; p < 10; ++p) {
        f32x4 o;
        #pragma unroll
        for (int k = 0; k < 4; ++k) {
            const int oo = 4 * p + k;            // 0..39 (compile-time)
            const int u  = oo / 5;
            const int r  = oo - u * 5;
            const int j  = u + r;                // window index, 0..11 (static)
            const float wv = (j < 4) ? w0[j] : (j < 8) ? w1[j - 4] : w2[j - 8];
            const uint32_t bit =
                (oo < 32) ? ((m0 >> oo) & 1u) : ((m1 >> (oo - 32)) & 1u);
            o[k] = bit ? wv : 0.0f;
        }
        *reinterpret_cast<f32x4*>(orow + 4 * p) = o;
    }
}

extern "C" void kernel_launch(void* const* d_in, const int* in_sizes, int n_in,
                              void* d_out, int out_size, void* d_ws, size_t ws_size,
                              hipStream_t stream) {
    const float* x  = (const float*)d_in[0];
    const float* rv = (const float*)d_in[1];
    float* out      = (float*)d_out;
    uint32_t* mask  = (uint32_t*)d_ws;      // 12.8 KB scratch

    hipLaunchKernelGGL(build_mask_kernel, dim3(400), dim3(256), 0, stream, rv, mask);

    dim3 block(256);
    dim3 grid(10240);                       // 1024 images x 10 chunks, linear
    hipLaunchKernelGGL(expand_cps_dropout_kernel, grid, block, 0, stream,
                       x, mask, out);
}

// Round 16
// 83.009 us; speedup vs baseline: 1.7863x; 1.6555x over previous
//
#include <hip/hip_runtime.h>
#include <stdint.h>

// Expansion + checkerboard-preserving dropout.  [BEST KNOWN — R12 structure]
// Phase 1: ballot mask kernel — one thread per mask BIT (102400 bits); each wave
//          covers 64 consecutive bits of one row (320 = 5*64); lanes 0/32 store
//          the packed u32 words. Final mask = (rand>0.25 | center) & in-bounds.
// Phase 2: fill-shaped main kernel: 512-thread blocks, each block = 32 contiguous
//          output rows (40 KB), flat LINEAR block->address mapping, grid = 10240
//          = exactly 10 residency rounds of 4 blocks/CU. Stage 12 x rows + 320
//          mask words via global_load_lds; 5 wave-contiguous float4 stores per
//          thread; all x gathers via LDS (VMEM scalar gathers are 1.8x slower,
//          R14; per-thread-segment stores are 1.65x slower, R15).

#define KEEP_SCALE (1.0f / 0.75f)

typedef float f32x4 __attribute__((ext_vector_type(4)));

__global__ __launch_bounds__(256) void build_mask_kernel(
    const float* __restrict__ rv,       // (320,320)
    uint32_t* __restrict__ mask)        // 3200 words, 10 per row
{
    const int g  = blockIdx.x * 256 + threadIdx.x;  // bit index, 0..102399
    const int oh = g / 320;
    const int ow = g - oh * 320;

    int qh = oh / 5, rh = oh - qh * 5;
    int ih = qh + rh - 2;
    int q  = ow / 5, r  = ow - q * 5;
    int iw = q + r - 2;

    float v = rv[g];                    // coalesced: 64 consecutive floats/wave
    bool keep = ((v > 0.25f) || (rh == 2 && r == 2))
                && ((unsigned)ih < 64u) && ((unsigned)iw < 64u);

    unsigned long long bal = __ballot(keep);
    int lane = threadIdx.x & 63;
    if (lane == 0)
        mask[g >> 5] = (uint32_t)bal;
    else if (lane == 32)
        mask[g >> 5] = (uint32_t)(bal >> 32);
}

__global__ __launch_bounds__(512) void expand_cps_dropout_kernel(
    const float* __restrict__ x,        // (1024, 64, 64)
    const uint32_t* __restrict__ mask,  // 3200 words (bounds folded in)
    float* __restrict__ out)            // (1024, 320, 320)
{
    __shared__ __align__(16) float    xs[12 * 64];  // 3072 B: rows [s0, s0+12)
    __shared__ __align__(16) uint32_t ms[320];      // 1280 B: 32 rows x 10 words

    const int t  = threadIdx.x;         // 0..511
    const int b  = blockIdx.x;          // 0..10239, LINEAR over output
    const int bc = b / 10;              // image
    const int rg = b - bc * 10;         // 32-row chunk within image

    const int a = 32 * rg;              // first output row of this block
    int s0 = a / 5 - 2;                 // first staged source row
    s0 = s0 < 0 ? 0 : (s0 > 52 ? 52 : s0);

    // ---- stage: x = 192 chunks (t 0..191), mask = 80 chunks (t 192..271) ----
    if (t < 192) {
        const float* xsrc = x + (size_t)bc * 4096 + s0 * 64;
        __builtin_amdgcn_global_load_lds(
            (const __attribute__((address_space(1))) void*)(xsrc + t * 4),
            (__attribute__((address_space(3))) void*)(xs + (t & ~63) * 4),
            16, 0, 0);
    } else if (t < 272) {
        int i = t - 192;
        const uint32_t* msrc = mask + rg * 320;     // rows a..a+31 -> words a*10..
        __builtin_amdgcn_global_load_lds(
            (const __attribute__((address_space(1))) void*)(msrc + i * 4),
            (__attribute__((address_space(3))) void*)(ms + (i & ~63) * 4),
            16, 0, 0);
    }

    // ---- per-thread patterns for the 5 stores (computed during stage wait) ----
    int      xoffB[5][4];               // byte offsets within staged row
    int      rowB[5];                   // staged-row byte offset
    int      soffF[5];                  // output float offset within chunk
    int      midx[5];                   // mask word index
    uint32_t msh_[5];                   // shift within word
    #pragma unroll
    for (int ji = 0; ji < 5; ++ji) {
        int f  = t + 512 * ji;          // 0..2559 (block covers 2560 float4)
        int r0 = f / 80;                // local row 0..31
        int o4 = f - r0 * 80;           // float4 index in row
        int ow = o4 * 4;
        soffF[ji] = r0 * 320 + ow;
        msh_[ji]  = (uint32_t)((o4 & 7) * 4);
        midx[ji]  = r0 * 10 + (o4 >> 3);
        int oh = a + r0;
        int q = oh / 5, r = oh - q * 5;
        int ihrel = q + r - 2 - s0;
        ihrel = ihrel < 0 ? 0 : (ihrel > 11 ? 11 : ihrel);  // mask kills OOB
        rowB[ji] = ihrel * 256;
        #pragma unroll
        for (int k = 0; k < 4; ++k) {
            int o = ow + k;
            int qq = o / 5, rr = o - qq * 5;
            int iw = qq + rr - 2;
            iw = iw < 0 ? 0 : (iw > 63 ? 63 : iw);          // mask kills OOB
            xoffB[ji][k] = iw * 4;
        }
    }

    __syncthreads();                    // drains vmcnt, then barrier

    uint32_t mb[5];
    #pragma unroll
    for (int ji = 0; ji < 5; ++ji)
        mb[ji] = ms[midx[ji]] >> msh_[ji];

    float* ob = out + (size_t)b * 10240;      // linear 40 KB chunk
    const char* xsb = (const char*)xs;

    #pragma unroll
    for (int ji = 0; ji < 5; ++ji) {
        const char* xr = xsb + rowB[ji];
        uint32_t m = mb[ji];
        f32x4 o;
        o.x = (m & 1u) ? *(const float*)(xr + xoffB[ji][0]) * KEEP_SCALE : 0.0f;
        o.y = (m & 2u) ? *(const float*)(xr + xoffB[ji][1]) * KEEP_SCALE : 0.0f;
        o.z = (m & 4u) ? *(const float*)(xr + xoffB[ji][2]) * KEEP_SCALE : 0.0f;
        o.w = (m & 8u) ? *(const float*)(xr + xoffB[ji][3]) * KEEP_SCALE : 0.0f;
        *reinterpret_cast<f32x4*>(ob + soffF[ji]) = o;
    }
}

extern "C" void kernel_launch(void* const* d_in, const int* in_sizes, int n_in,
                              void* d_out, int out_size, void* d_ws, size_t ws_size,
                              hipStream_t stream) {
    const float* x  = (const float*)d_in[0];
    const float* rv = (const float*)d_in[1];
    float* out      = (float*)d_out;
    uint32_t* mask  = (uint32_t*)d_ws;      // 12.8 KB scratch

    hipLaunchKernelGGL(build_mask_kernel, dim3(400), dim3(256), 0, stream, rv, mask);

    dim3 block(512);
    dim3 grid(10240);                       // 1024 images x 10 chunks, linear
    hipLaunchKernelGGL(expand_cps_dropout_kernel, grid, block, 0, stream,
                       x, mask, out);
}